// Round 1
// baseline (1983.729 us; speedup 1.0000x reference)
//
#include <hip/hip_runtime.h>
#include <hip/hip_bf16.h>

#define LEAK 0.2f

// ---------------------------------------------------------------------------
// Generic direct conv + leaky ReLU.
// Grid: x = spatial blocks (OH*OW / 256, padded), y = b*(CO/8) + cog
// Each thread: 1 output pixel x 8 consecutive output channels.
// Weight/bias indices are wave-uniform (blockIdx.y + loop vars) -> scalar loads.
// ---------------------------------------------------------------------------
template<int CI, int CO, int K, int ST, int P, int IH, int IW, int OH, int OW>
__global__ __launch_bounds__(256) void conv_k(const float* __restrict__ x,
                                              const float* __restrict__ w,
                                              const float* __restrict__ bias,
                                              float* __restrict__ y) {
    int sp = blockIdx.x * 256 + threadIdx.x;
    if (sp >= OH * OW) return;
    int ow = sp % OW;
    int oh = sp / OW;
    int bg = blockIdx.y;                 // b*(CO/8) + cog
    int cog = bg % (CO / 8);
    int b   = bg / (CO / 8);

    float acc[8];
#pragma unroll
    for (int j = 0; j < 8; ++j) acc[j] = bias[cog * 8 + j];

    const float* __restrict__ xb = x + (size_t)b * CI * IH * IW;
    const float* __restrict__ wg = w + (size_t)(cog * 8) * CI * K * K;

    for (int ci = 0; ci < CI; ++ci) {
#pragma unroll
        for (int kh = 0; kh < K; ++kh) {
            int ih = oh * ST + kh - P;
            if ((unsigned)ih >= (unsigned)IH) continue;
#pragma unroll
            for (int kw = 0; kw < K; ++kw) {
                int iw = ow * ST + kw - P;
                if ((unsigned)iw >= (unsigned)IW) continue;
                float v = xb[(ci * IH + ih) * IW + iw];
#pragma unroll
                for (int j = 0; j < 8; ++j)
                    acc[j] += v * wg[(j * CI + ci) * K * K + kh * K + kw];
            }
        }
    }

    float* __restrict__ yo = y + (((size_t)b * CO + cog * 8) * OH + oh) * OW + ow;
#pragma unroll
    for (int j = 0; j < 8; ++j) {
        float a = acc[j];
        yo[(size_t)j * OH * OW] = a > 0.0f ? a : LEAK * a;
    }
}

// ---------------------------------------------------------------------------
// ROI bilinear sampling. One block per (b, r). Output layout S[b][c][r][p]
// (p = i*10+j), which is byte-identical to the reference's reshape quirk:
// samp (C, R*100) -> reshape (R, C, 10, 10) means roi_feat[b] memory == [c][r][p].
// ---------------------------------------------------------------------------
__global__ __launch_bounds__(256) void roi_k(const float* __restrict__ feat,
                                             const float* __restrict__ roi,
                                             float* __restrict__ S) {
    int b = blockIdx.x >> 5;      // / 32
    int r = blockIdx.x & 31;
    const float* rr = roi + (size_t)(b * 32 + r) * 7;

    __shared__ int   offA[100], offB[100], offC[100], offD[100];
    __shared__ float wA[100], wB[100], wC[100], wD[100];

    int tid = threadIdx.x;
    if (tid < 100) {
        int i = tid / 10, j = tid % 10;
        float cx = rr[0], cy = rr[1];
        float W1 = rr[2], W2 = rr[3], H1 = rr[4], H2 = rr[5], psi = rr[6];
        float offx = ((float)j - 4.5f) / 10.0f;
        float offy = ((float)i - 4.5f) / 10.0f;
        float gx = offx * (W1 + W2) - (W1 - W2) * 0.5f;
        float gy = offy * (H1 + H2) - (H1 - H2) * 0.5f;
        float sn = sinf(psi), cs = cosf(psi);
        float xs = gx * cs + gy * sn + cx;   // einsum with rotM=[[c,-s],[s,c]]
        float ys = -gx * sn + gy * cs + cy;

        float x0f = floorf(xs), y0f = floorf(ys);
        int x0 = (int)x0f, x1 = x0 + 1;
        int y0 = (int)y0f, y1 = y0 + 1;
        x0 = min(max(x0, 0), 55); x1 = min(max(x1, 0), 55);
        y0 = min(max(y0, 0), 55); y1 = min(max(y1, 0), 55);
        float fx0 = (float)x0, fx1 = (float)x1;
        float fy0 = (float)y0, fy1 = (float)y1;
        float step = (fx1 - fx0) * (fy1 - fy0);
        step = fminf(fmaxf(step, 0.001f), 2.0f);
        float inv = 1.0f / step;
        wA[tid] = (fx1 - xs) * (fy1 - ys) * inv;
        wB[tid] = (fx1 - xs) * (ys - fy0) * inv;
        wC[tid] = (xs - fx0) * (fy1 - ys) * inv;
        wD[tid] = (xs - fx0) * (ys - fy0) * inv;
        offA[tid] = y0 * 56 + x0;
        offB[tid] = y1 * 56 + x0;
        offC[tid] = y0 * 56 + x1;
        offD[tid] = y1 * 56 + x1;
    }
    __syncthreads();

    const float* __restrict__ fb = feat + (size_t)b * 128 * 3136;
    float* __restrict__ outb = S + ((size_t)b * 128 * 32 + r) * 100;  // + c*3200 + p
    for (int t = tid; t < 12800; t += 256) {
        int c = t / 100, p = t - c * 100;
        const float* f = fb + c * 3136;
        float v = wA[p] * f[offA[p]] + wB[p] * f[offB[p]] +
                  wC[p] * f[offC[p]] + wD[p] * f[offD[p]];
        outb[(size_t)c * 3200 + p] = v;
    }
}

// ---------------------------------------------------------------------------
// FC: OUT[m][n] = dot(S_flat[m, :12800], fc_w[n, :12800]) + fc_b[n]
// M=1024, N=256, K=12800. 32x32 block tile, BK=32, 2x2 micro-tile.
// Grid: (N/32=8, M/32=32) = 256 blocks x 256 threads.
// ---------------------------------------------------------------------------
__global__ __launch_bounds__(256) void fc_k(const float* __restrict__ A,
                                            const float* __restrict__ Wt,
                                            const float* __restrict__ bias,
                                            float* __restrict__ out) {
    __shared__ float As[32][34];   // [k][m], +2 pad keeps float2 reads aligned
    __shared__ float Ws[32][34];   // [k][n]

    int tid = threadIdx.x;
    int bn = blockIdx.x, bm = blockIdx.y;
    int tx = tid & 15;        // n pair
    int ty = tid >> 4;        // m pair
    int lr = tid >> 3;        // 0..31 tile row for loading
    int lc = tid & 7;         // 0..7  float4 col for loading

    float c00 = 0.f, c01 = 0.f, c10 = 0.f, c11 = 0.f;

    const float* __restrict__ Arow = A  + (size_t)(bm * 32 + lr) * 12800 + lc * 4;
    const float* __restrict__ Wrow = Wt + (size_t)(bn * 32 + lr) * 12800 + lc * 4;

    for (int k0 = 0; k0 < 12800; k0 += 32) {
        float4 a4 = *(const float4*)(Arow + k0);
        float4 w4 = *(const float4*)(Wrow + k0);
        __syncthreads();
        As[lc * 4 + 0][lr] = a4.x; As[lc * 4 + 1][lr] = a4.y;
        As[lc * 4 + 2][lr] = a4.z; As[lc * 4 + 3][lr] = a4.w;
        Ws[lc * 4 + 0][lr] = w4.x; Ws[lc * 4 + 1][lr] = w4.y;
        Ws[lc * 4 + 2][lr] = w4.z; Ws[lc * 4 + 3][lr] = w4.w;
        __syncthreads();
#pragma unroll
        for (int k = 0; k < 32; ++k) {
            float2 av = *(const float2*)&As[k][2 * ty];
            float2 wv = *(const float2*)&Ws[k][2 * tx];
            c00 += av.x * wv.x; c01 += av.x * wv.y;
            c10 += av.y * wv.x; c11 += av.y * wv.y;
        }
    }

    int m = bm * 32 + 2 * ty;
    int n = bn * 32 + 2 * tx;
    float b0 = bias[n], b1 = bias[n + 1];
    out[(size_t)m * 256 + n]           = c00 + b0;
    out[(size_t)m * 256 + n + 1]       = c01 + b1;
    out[(size_t)(m + 1) * 256 + n]     = c10 + b0;
    out[(size_t)(m + 1) * 256 + n + 1] = c11 + b1;
}

// ---------------------------------------------------------------------------
extern "C" void kernel_launch(void* const* d_in, const int* in_sizes, int n_in,
                              void* d_out, int out_size, void* d_ws, size_t ws_size,
                              hipStream_t stream) {
    const float* x   = (const float*)d_in[0];
    const float* ROI = (const float*)d_in[1];
    const float* w1  = (const float*)d_in[2];
    const float* b1  = (const float*)d_in[3];
    const float* w2  = (const float*)d_in[4];
    const float* b2  = (const float*)d_in[5];
    const float* w3  = (const float*)d_in[6];
    const float* b3  = (const float*)d_in[7];
    const float* fcw = (const float*)d_in[8];
    const float* fcb = (const float*)d_in[9];
    float* out = (float*)d_out;

    char* ws = (char*)d_ws;
    // conv1 out: 32*32*112*112*4 = 51,380,224 B at offset 0
    // conv2 out: 32*64*56*56*4   = 25,690,112 B at offset 51,380,224
    // conv3 out: 32*128*56*56*4  = 51,380,224 B at offset 77,070,336
    // S (roi samples): 32*128*32*100*4 = 52,428,800 B at offset 0
    //   (overlaps conv1 out + first 1 MB of conv2 out, both dead by then)
    float* c1 = (float*)(ws);
    float* c2 = (float*)(ws + 51380224);
    float* c3 = (float*)(ws + 77070336);
    float* S  = (float*)(ws);

    // conv1: (32,3,224,224) -> (32,32,112,112), K=5,S=2,P=2
    conv_k<3, 32, 5, 2, 2, 224, 224, 112, 112>
        <<<dim3(49, 32 * 4), 256, 0, stream>>>(x, w1, b1, c1);
    // conv2: -> (32,64,56,56), K=5,S=2,P=2
    conv_k<32, 64, 5, 2, 2, 112, 112, 56, 56>
        <<<dim3(13, 32 * 8), 256, 0, stream>>>(c1, w2, b2, c2);
    // conv3: -> (32,128,56,56), K=3,S=1,P=1
    conv_k<64, 128, 3, 1, 1, 56, 56, 56, 56>
        <<<dim3(13, 32 * 16), 256, 0, stream>>>(c2, w3, b3, c3);
    // ROI sampling -> S[b][c][r][p]
    roi_k<<<1024, 256, 0, stream>>>(c3, ROI, S);
    // FC: (1024 x 12800) @ (12800 x 256) + bias
    fc_k<<<dim3(8, 32), 256, 0, stream>>>(S, fcw, fcb, out);
}

// Round 2
// 1103.804 us; speedup vs baseline: 1.7972x; 1.7972x over previous
//
#include <hip/hip_runtime.h>
#include <hip/hip_bf16.h>

#define LEAK 0.2f

// ---------------------------------------------------------------------------
// LDS-tiled direct conv + leaky ReLU.
// Block = (batch b, channel-group cog of CPT, output tile TH x TW).
// Stage CC input channels (zero-padded) into LDS, then branch-free compute:
// each thread = 1 output pixel x CPT output channels.
// Weights are wave-uniform -> scalar loads; 16 FMAs per LDS value.
// ---------------------------------------------------------------------------
template<int CI, int CO, int K, int ST, int P, int IH, int IW, int OH, int OW,
         int TH, int TW, int CC, int CPT>
__global__ __launch_bounds__(256) void conv_tile_k(const float* __restrict__ x,
                                                   const float* __restrict__ w,
                                                   const float* __restrict__ bias,
                                                   float* __restrict__ y) {
    constexpr int ITH = (TH - 1) * ST + K;
    constexpr int ITW = (TW - 1) * ST + K;
    constexpr int RP  = (ITW & 1) ? ITW : ITW + 1;  // odd row stride: spread banks
    constexpr int NTW = OW / TW;
    constexpr int COG = CO / CPT;

    __shared__ float tile[CC][ITH][RP];

    int tid = threadIdx.x;
    int tr = blockIdx.x / NTW, tc = blockIdx.x % NTW;
    int bg  = blockIdx.y;
    int cog = bg % COG;
    int b   = bg / COG;

    int th0 = tr * TH, tw0 = tc * TW;
    int ih_base = th0 * ST - P;
    int iw_base = tw0 * ST - P;

    int wid = tid >> 6, lane = tid & 63;
    int ty = tid / TW, tx = tid % TW;
    bool active = tid < TH * TW;

    float acc[CPT];
#pragma unroll
    for (int j = 0; j < CPT; ++j) acc[j] = bias[cog * CPT + j];

    const float* __restrict__ xb = x + (size_t)b * CI * IH * IW;

    for (int ci0 = 0; ci0 < CI; ci0 += CC) {
        __syncthreads();
        // ---- stage CC channels, zero-fill out-of-bounds ----
        for (int p = wid; p < CC * ITH; p += 4) {
            int cc = p / ITH, row = p - cc * ITH;
            int ih = ih_base + row;
            const float* src = xb + ((size_t)(ci0 + cc) * IH + ih) * IW;
            bool rowok = (unsigned)ih < (unsigned)IH;
            for (int col = lane; col < ITW; col += 64) {
                int iw = iw_base + col;
                float v = 0.0f;
                if (rowok && (unsigned)iw < (unsigned)IW) v = src[iw];
                tile[cc][row][col] = v;
            }
        }
        __syncthreads();

        // ---- branch-free compute ----
        if (active) {
            for (int cc = 0; cc < CC; ++cc) {
                float xv[K * K];
#pragma unroll
                for (int kh = 0; kh < K; ++kh)
#pragma unroll
                    for (int kw = 0; kw < K; ++kw)
                        xv[kh * K + kw] = tile[cc][ty * ST + kh][tx * ST + kw];
                const float* wp = w + ((size_t)(cog * CPT) * CI + (ci0 + cc)) * (K * K);
#pragma unroll
                for (int j = 0; j < CPT; ++j) {
                    const float* __restrict__ wj = wp + (size_t)j * CI * K * K;
#pragma unroll
                    for (int q = 0; q < K * K; ++q)
                        acc[j] += xv[q] * wj[q];
                }
            }
        }
    }

    if (active) {
        int oh = th0 + ty, ow = tw0 + tx;
        float* __restrict__ yo = y + (((size_t)b * CO + cog * CPT) * OH + oh) * OW + ow;
#pragma unroll
        for (int j = 0; j < CPT; ++j) {
            float a = acc[j];
            yo[(size_t)j * OH * OW] = a > 0.0f ? a : LEAK * a;
        }
    }
}

// ---------------------------------------------------------------------------
// ROI bilinear sampling. One block per (b, r). Output layout S[b][c][r][p]
// byte-identical to the reference reshape quirk.
// ---------------------------------------------------------------------------
__global__ __launch_bounds__(256) void roi_k(const float* __restrict__ feat,
                                             const float* __restrict__ roi,
                                             float* __restrict__ S) {
    int b = blockIdx.x >> 5;
    int r = blockIdx.x & 31;
    const float* rr = roi + (size_t)(b * 32 + r) * 7;

    __shared__ int   offA[100], offB[100], offC[100], offD[100];
    __shared__ float wA[100], wB[100], wC[100], wD[100];

    int tid = threadIdx.x;
    if (tid < 100) {
        int i = tid / 10, j = tid % 10;
        float cx = rr[0], cy = rr[1];
        float W1 = rr[2], W2 = rr[3], H1 = rr[4], H2 = rr[5], psi = rr[6];
        float offx = ((float)j - 4.5f) / 10.0f;
        float offy = ((float)i - 4.5f) / 10.0f;
        float gx = offx * (W1 + W2) - (W1 - W2) * 0.5f;
        float gy = offy * (H1 + H2) - (H1 - H2) * 0.5f;
        float sn = sinf(psi), cs = cosf(psi);
        float xs = gx * cs + gy * sn + cx;
        float ys = -gx * sn + gy * cs + cy;

        float x0f = floorf(xs), y0f = floorf(ys);
        int x0 = (int)x0f, x1 = x0 + 1;
        int y0 = (int)y0f, y1 = y0 + 1;
        x0 = min(max(x0, 0), 55); x1 = min(max(x1, 0), 55);
        y0 = min(max(y0, 0), 55); y1 = min(max(y1, 0), 55);
        float fx0 = (float)x0, fx1 = (float)x1;
        float fy0 = (float)y0, fy1 = (float)y1;
        float step = (fx1 - fx0) * (fy1 - fy0);
        step = fminf(fmaxf(step, 0.001f), 2.0f);
        float inv = 1.0f / step;
        wA[tid] = (fx1 - xs) * (fy1 - ys) * inv;
        wB[tid] = (fx1 - xs) * (ys - fy0) * inv;
        wC[tid] = (xs - fx0) * (fy1 - ys) * inv;
        wD[tid] = (xs - fx0) * (ys - fy0) * inv;
        offA[tid] = y0 * 56 + x0;
        offB[tid] = y1 * 56 + x0;
        offC[tid] = y0 * 56 + x1;
        offD[tid] = y1 * 56 + x1;
    }
    __syncthreads();

    const float* __restrict__ fb = feat + (size_t)b * 128 * 3136;
    float* __restrict__ outb = S + ((size_t)b * 128 * 32 + r) * 100;
    for (int t = tid; t < 12800; t += 256) {
        int c = t / 100, p = t - c * 100;
        const float* f = fb + c * 3136;
        float v = wA[p] * f[offA[p]] + wB[p] * f[offB[p]] +
                  wC[p] * f[offC[p]] + wD[p] * f[offD[p]];
        outb[(size_t)c * 3200 + p] = v;
    }
}

// ---------------------------------------------------------------------------
// FC split-K GEMM: part[ks][m][n] = sum over K-slice of A[m,k]*Wt[n,k]
// M=1024 N=256 K=12800, 8 K-splits of 1600. 64x64 tile, BK=16, 4x4 micro.
// Grid (4, 16, 8) = 512 blocks x 256 threads.
// ---------------------------------------------------------------------------
__global__ __launch_bounds__(256) void fc_gemm_k(const float* __restrict__ A,
                                                 const float* __restrict__ Wt,
                                                 float* __restrict__ part) {
    constexpr int BK = 16;
    constexpr int KSLICE = 1600;
    __shared__ float As[BK][64];   // [k][m]
    __shared__ float Ws[BK][64];   // [k][n]

    int tid = threadIdx.x;
    int bn = blockIdx.x, bm = blockIdx.y, ks = blockIdx.z;
    int tx = tid & 15, ty = tid >> 4;
    int lm = tid >> 2;             // 0..63 row
    int lk = (tid & 3) * 4;        // 0,4,8,12

    float c[4][4] = {};

    const float* __restrict__ Ab = A  + (size_t)(bm * 64 + lm) * 12800 + ks * KSLICE + lk;
    const float* __restrict__ Wb = Wt + (size_t)(bn * 64 + lm) * 12800 + ks * KSLICE + lk;

    for (int k0 = 0; k0 < KSLICE; k0 += BK) {
        float4 a4 = *(const float4*)(Ab + k0);
        float4 w4 = *(const float4*)(Wb + k0);
        __syncthreads();
        As[lk + 0][lm] = a4.x; As[lk + 1][lm] = a4.y;
        As[lk + 2][lm] = a4.z; As[lk + 3][lm] = a4.w;
        Ws[lk + 0][lm] = w4.x; Ws[lk + 1][lm] = w4.y;
        Ws[lk + 2][lm] = w4.z; Ws[lk + 3][lm] = w4.w;
        __syncthreads();
#pragma unroll
        for (int k = 0; k < BK; ++k) {
            float4 av = *(const float4*)&As[k][ty * 4];
            float4 wv = *(const float4*)&Ws[k][tx * 4];
            c[0][0] += av.x * wv.x; c[0][1] += av.x * wv.y;
            c[0][2] += av.x * wv.z; c[0][3] += av.x * wv.w;
            c[1][0] += av.y * wv.x; c[1][1] += av.y * wv.y;
            c[1][2] += av.y * wv.z; c[1][3] += av.y * wv.w;
            c[2][0] += av.z * wv.x; c[2][1] += av.z * wv.y;
            c[2][2] += av.z * wv.z; c[2][3] += av.z * wv.w;
            c[3][0] += av.w * wv.x; c[3][1] += av.w * wv.y;
            c[3][2] += av.w * wv.z; c[3][3] += av.w * wv.w;
        }
    }

    float* __restrict__ po = part + ((size_t)ks * 1024 + bm * 64 + ty * 4) * 256
                                  + bn * 64 + tx * 4;
#pragma unroll
    for (int i = 0; i < 4; ++i) {
        float4 v = make_float4(c[i][0], c[i][1], c[i][2], c[i][3]);
        *(float4*)(po + (size_t)i * 256) = v;
    }
}

__global__ __launch_bounds__(256) void fc_reduce_k(const float* __restrict__ part,
                                                   const float* __restrict__ bias,
                                                   float* __restrict__ out) {
    int i = blockIdx.x * 256 + threadIdx.x;   // 0..262143, n = i & 255
    float s = bias[i & 255];
#pragma unroll
    for (int ks = 0; ks < 8; ++ks) s += part[(size_t)ks * 262144 + i];
    out[i] = s;
}

// ---------------------------------------------------------------------------
extern "C" void kernel_launch(void* const* d_in, const int* in_sizes, int n_in,
                              void* d_out, int out_size, void* d_ws, size_t ws_size,
                              hipStream_t stream) {
    const float* x   = (const float*)d_in[0];
    const float* ROI = (const float*)d_in[1];
    const float* w1  = (const float*)d_in[2];
    const float* b1  = (const float*)d_in[3];
    const float* w2  = (const float*)d_in[4];
    const float* b2  = (const float*)d_in[5];
    const float* w3  = (const float*)d_in[6];
    const float* b3  = (const float*)d_in[7];
    const float* fcw = (const float*)d_in[8];
    const float* fcb = (const float*)d_in[9];
    float* out = (float*)d_out;

    char* ws = (char*)d_ws;
    // c1: [0, 51,380,224)           32*32*112*112*4
    // c2: [51,380,224, 77,070,336)  32*64*56*56*4
    // c3: [77,070,336, 128,450,560) 32*128*56*56*4
    // S : [0, 52,428,800)           (c1 + head of c2 dead by ROI time)
    // part: [52,428,800, 61,817,408) 8*1024*256*4 (c2 dead by FC time)
    float* c1   = (float*)(ws);
    float* c2   = (float*)(ws + 51380224);
    float* c3   = (float*)(ws + 77070336);
    float* S    = (float*)(ws);
    float* part = (float*)(ws + 52428800);

    // conv1: (32,3,224,224) -> (32,32,112,112), K=5,S=2,P=2
    conv_tile_k<3, 32, 5, 2, 2, 224, 224, 112, 112, 4, 56, 3, 16>
        <<<dim3(28 * 2, 32 * 2), 256, 0, stream>>>(x, w1, b1, c1);
    // conv2: -> (32,64,56,56), K=5,S=2,P=2
    conv_tile_k<32, 64, 5, 2, 2, 112, 112, 56, 56, 4, 56, 4, 16>
        <<<dim3(14, 32 * 4), 256, 0, stream>>>(c1, w2, b2, c2);
    // conv3: -> (32,128,56,56), K=3,S=1,P=1
    conv_tile_k<64, 128, 3, 1, 1, 56, 56, 56, 56, 4, 56, 16, 16>
        <<<dim3(14, 32 * 8), 256, 0, stream>>>(c2, w3, b3, c3);
    // ROI sampling -> S[b][c][r][p]
    roi_k<<<1024, 256, 0, stream>>>(c3, ROI, S);
    // FC split-K + reduce
    fc_gemm_k<<<dim3(4, 16, 8), 256, 0, stream>>>(S, fcw, part);
    fc_reduce_k<<<1024, 256, 0, stream>>>(part, fcb, out);
}